// Round 5
// baseline (560.076 us; speedup 1.0000x reference)
//
#include <hip/hip_runtime.h>

// AFDChannelAttention on MI355X — fp32 in/out (x: [32,512,64,64] float32).
// rows BC=16384, L=4096, N_BASIS=64, R=0.9.
// proj = X*B^T via bf16 MFMA with hi/lo split of BOTH operands (3 chains,
// fp32-quality logits), softmax(|proj|), out = x + W*B (bf16 MFMA, fp32 add).
//
// v4 (on top of v3's LDS-staged contiguous-HBM structure):
//  - xbuf stride 260 -> 268 (stride = 12 mod 32 banks): fragment reads hit
//    all 8 16B-slots, 2 lanes/slot = conflict-free (v3 was 8-way, 19.4M
//    conflict cycles). projp stride 68 -> 64 (row constant per 16-lane
//    group, reads conflict-free; keeps LDS <= 53.8 KB for 3 blocks/CU).
//  - Depth-2 register prefetch of the x stream (stA/stB, manual 2-chunk
//    unroll): loads issued at chunk c are consumed at c+2 (~2 chunk walls
//    ~900+ cyc) -> vmcnt stall before ds_write eliminated.
//  - GEMM2: double-buffered ctile -> 1 barrier per chunk (was 2), and
//    next-chunk x prefetch issued before the barrier.

typedef short s16x8 __attribute__((ext_vector_type(8)));
typedef float f32x4 __attribute__((ext_vector_type(4)));

#define MFMA16(a, b, c) __builtin_amdgcn_mfma_f32_16x16x32_bf16((a), (b), (c), 0, 0, 0)

#define L_DIM   4096
#define N_BASIS 64
#define BC      16384

__device__ __forceinline__ float bf2f(ushort u) {
    union { unsigned int i; float f; } v; v.i = ((unsigned int)u) << 16; return v.f;
}
__device__ __forceinline__ ushort f2bf(float f) {
    union { float f; unsigned int i; } v; v.f = f;
    unsigned int i = v.i;
    return (ushort)((i + 0x7FFFu + ((i >> 16) & 1u)) >> 16);   // RNE
}

// ---------------------------------------------------------------------------
// Kernel 1: Blaschke basis, pre-swizzled into MFMA B-operand fragment layout.
//  b1h/b1l (GEMM1, K=l, col=n): elem (n,l) at ((l/8)*64+n)*8 + l%8
//  b2h     (GEMM2, K=n, col=l): elem (n,l) at ((n/8)*4096+l)*8 + n%8
// ---------------------------------------------------------------------------
__global__ __launch_bounds__(256) void afd_basis_kernel(ushort* __restrict__ b1h,
                                                        ushort* __restrict__ b1l,
                                                        ushort* __restrict__ b2h) {
    int idx = blockIdx.x * 256 + threadIdx.x;      // 0 .. 64*4096-1
    int n = idx & 63;
    int l = idx >> 6;
    // t_l = 2pi*l/4095 (endpoint=True), theta_n = 2pi*n/64 (endpoint=False)
    double ph = 6.283185307179586 * ((double)l / 4095.0 - (double)n / 64.0);
    float c = cosf((float)ph);
    float rc = 0.9f * c;
    float B = 0.435889894354f * (1.0f - rc) / (1.81f - 2.0f * rc);
    ushort hi = f2bf(B);
    float lo = B - bf2f(hi);
    ushort lo16 = f2bf(lo);
    int i1 = ((l >> 3) * 64 + n) * 8 + (l & 7);
    b1h[i1] = hi;
    b1l[i1] = lo16;
    int i2 = ((n >> 3) * 4096 + l) * 8 + (n & 7);
    b2h[i2] = hi;
}

// ---------------------------------------------------------------------------
// Kernel 2: fused proj -> softmax -> attn -> add, 16 rows per block.
// 256 threads = 4 waves.
// ---------------------------------------------------------------------------
__global__ __launch_bounds__(256, 3) void afd_main_kernel(const float* __restrict__ x,
                                                          float* __restrict__ out,
                                                          const ushort* __restrict__ b1h,
                                                          const ushort* __restrict__ b1l,
                                                          const ushort* __restrict__ b2h) {
    union SMem {
        struct {
            float xbuf[2][16][268];   // stride 268: 12 mod 32 banks -> conflict-free frag reads
            float projp[4][16][64];   // split-K partials (row const per 16-lane read group)
        } g1;
        float ctile[2][16][268];       // GEMM2 epilogue tile, double-buffered
    };
    __shared__ SMem sm;
    __shared__ __align__(16) ushort wbf[16][64];
    __shared__ float red[16][16];
    __shared__ float rowstat[16];

    const int tid  = threadIdx.x;
    const int wave = tid >> 6;
    const int lane = tid & 63;
    const int l16  = lane & 15;
    const int q    = lane >> 4;
    const int rb   = blockIdx.x * 16;
    const int srow = wave * 4;          // rows this wave stages / RMWs

    // ---------------- GEMM1: LDS-staged x, split-K across waves -----------
    const float* xsrc = x + (size_t)(rb + srow) * L_DIM + lane * 4;

    f32x4 stA[4], stB[4];
    {   // chunk 0 straight to LDS
        f32x4 s0[4];
#pragma unroll
        for (int rr = 0; rr < 4; ++rr)
            s0[rr] = *(const f32x4*)(xsrc + (size_t)rr * L_DIM);
#pragma unroll
        for (int rr = 0; rr < 4; ++rr)
            *(f32x4*)&sm.g1.xbuf[0][srow + rr][lane * 4] = s0[rr];
    }
#pragma unroll
    for (int rr = 0; rr < 4; ++rr)
        stA[rr] = *(const f32x4*)(xsrc + (size_t)rr * L_DIM + 256);   // chunk 1
#pragma unroll
    for (int rr = 0; rr < 4; ++rr)
        stB[rr] = *(const f32x4*)(xsrc + (size_t)rr * L_DIM + 512);   // chunk 2
    asm volatile("s_waitcnt lgkmcnt(0)" ::: "memory");
    __builtin_amdgcn_s_barrier();

    f32x4 acc[3][4];   // [chain hh/hl/lh][n-tile]
#pragma unroll
    for (int ch = 0; ch < 3; ++ch)
#pragma unroll
        for (int t = 0; t < 4; ++t) acc[ch][t] = (f32x4){0.f, 0.f, 0.f, 0.f};

    const ushort* bh_base = b1h + l16 * 8 + q * 512;
    const ushort* bl_base = b1l + l16 * 8 + q * 512;
    const int koff = wave * 64 + q * 8;      // within-chunk read offset

    auto g1_compute = [&](int cc, int bb) {
#pragma unroll
        for (int ks = 0; ks < 2; ++ks) {
            const int k0 = cc * 256 + wave * 64 + ks * 32;   // absolute k
            f32x4 x0 = *(const f32x4*)&sm.g1.xbuf[bb][l16][koff + ks * 32];
            f32x4 x1 = *(const f32x4*)&sm.g1.xbuf[bb][l16][koff + ks * 32 + 4];
            s16x8 xh, xl;
#pragma unroll
            for (int j = 0; j < 4; ++j) {
                ushort h0 = f2bf(x0[j]);
                xh[j] = (short)h0;
                xl[j] = (short)f2bf(x0[j] - bf2f(h0));
                ushort h1 = f2bf(x1[j]);
                xh[4 + j] = (short)h1;
                xl[4 + j] = (short)f2bf(x1[j] - bf2f(h1));
            }
            const ushort* bh = bh_base + ((size_t)k0 << 6);
            const ushort* bl = bl_base + ((size_t)k0 << 6);
#pragma unroll
            for (int t = 0; t < 4; ++t) {
                s16x8 vh = *(const s16x8*)(bh + t * 128);
                s16x8 vl = *(const s16x8*)(bl + t * 128);
                acc[0][t] = MFMA16(xh, vh, acc[0][t]);
                acc[1][t] = MFMA16(xh, vl, acc[1][t]);
                acc[2][t] = MFMA16(xl, vh, acc[2][t]);
            }
        }
    };

#pragma unroll 1
    for (int c2 = 0; c2 < 16; c2 += 2) {
        // ---- even chunk c2 (buf 0); stA holds chunk c2+1 ----
        g1_compute(c2, 0);
#pragma unroll
        for (int rr = 0; rr < 4; ++rr)
            *(f32x4*)&sm.g1.xbuf[1][srow + rr][lane * 4] = stA[rr];
        if (c2 + 3 < 16) {
#pragma unroll
            for (int rr = 0; rr < 4; ++rr)
                stA[rr] = *(const f32x4*)(xsrc + (size_t)rr * L_DIM + (c2 + 3) * 256);
        }
        asm volatile("s_waitcnt lgkmcnt(0)" ::: "memory");
        __builtin_amdgcn_s_barrier();

        // ---- odd chunk c2+1 (buf 1); stB holds chunk c2+2 ----
        g1_compute(c2 + 1, 1);
        if (c2 + 2 < 16) {
#pragma unroll
            for (int rr = 0; rr < 4; ++rr)
                *(f32x4*)&sm.g1.xbuf[0][srow + rr][lane * 4] = stB[rr];
            if (c2 + 4 < 16) {
#pragma unroll
                for (int rr = 0; rr < 4; ++rr)
                    stB[rr] = *(const f32x4*)(xsrc + (size_t)rr * L_DIM + (c2 + 4) * 256);
            }
            asm volatile("s_waitcnt lgkmcnt(0)" ::: "memory");
            __builtin_amdgcn_s_barrier();
        }
    }

    // C layout: col = lane&15 (= n within tile), row = q*4 + reg
#pragma unroll
    for (int t = 0; t < 4; ++t) {
        f32x4 p = acc[0][t] + (acc[1][t] + acc[2][t]);
#pragma unroll
        for (int r = 0; r < 4; ++r)
            sm.g1.projp[wave][q * 4 + r][t * 16 + l16] = p[r];
    }
    __syncthreads();

    // ---------------- softmax(|proj|) over n=64, per row ------------------
    {
        const int row = tid >> 4;       // 16 rows
        const int i   = tid & 15;       // 16 segments of 4 n each
        f32x4 s = *(const f32x4*)&sm.g1.projp[0][row][i * 4];
        s += *(const f32x4*)&sm.g1.projp[1][row][i * 4];
        s += *(const f32x4*)&sm.g1.projp[2][row][i * 4];
        s += *(const f32x4*)&sm.g1.projp[3][row][i * 4];
        float a0 = fabsf(s[0]), a1 = fabsf(s[1]);
        float a2 = fabsf(s[2]), a3 = fabsf(s[3]);
        red[row][i] = fmaxf(fmaxf(a0, a1), fmaxf(a2, a3));
        __syncthreads();
        if (tid < 16) {
            float rm = red[tid][0];
#pragma unroll
            for (int j = 1; j < 16; ++j) rm = fmaxf(rm, red[tid][j]);
            rowstat[tid] = rm;
        }
        __syncthreads();
        float rm = rowstat[row];
        float e0 = __expf(a0 - rm), e1 = __expf(a1 - rm);
        float e2 = __expf(a2 - rm), e3 = __expf(a3 - rm);
        red[row][i] = e0 + e1 + e2 + e3;
        __syncthreads();
        if (tid < 16) {
            float ss = red[tid][0];
#pragma unroll
            for (int j = 1; j < 16; ++j) ss += red[tid][j];
            rowstat[tid] = 1.0f / ss;
        }
        __syncthreads();
        float inv = rowstat[row];
        wbf[row][i * 4 + 0] = f2bf(e0 * inv);
        wbf[row][i * 4 + 1] = f2bf(e1 * inv);
        wbf[row][i * 4 + 2] = f2bf(e2 * inv);
        wbf[row][i * 4 + 3] = f2bf(e3 * inv);
    }
    __syncthreads();

    // ---------------- GEMM2: out = x + W * B (contiguous epilogue) --------
    s16x8 a0f = *(const s16x8*)&wbf[l16][q * 8];
    s16x8 a1f = *(const s16x8*)&wbf[l16][32 + q * 8];
    const f32x4 zero = {0.f, 0.f, 0.f, 0.f};
    const ushort* b2p = b2h + (q * 4096 + l16) * 8;
    const float* xep = x   + (size_t)(rb + srow) * L_DIM + lane * 4;
    float*       oep = out + (size_t)(rb + srow) * L_DIM + lane * 4;

    f32x4 xr[4], xr2[4];
#pragma unroll
    for (int rr = 0; rr < 4; ++rr)
        xr[rr] = *(const f32x4*)(xep + (size_t)rr * L_DIM);   // chunk 0 (L3-warm)

#pragma unroll 2
    for (int lc = 0; lc < 16; ++lc) {
        const int p = lc & 1;
        // compute C for 4 l-tiles of 16, write to ctile[p]
#pragma unroll
        for (int t = 0; t < 4; ++t) {
            const int l0 = lc * 256 + wave * 64 + t * 16;
            s16x8 b0  = *(const s16x8*)(b2p + ((size_t)l0 << 3));
            s16x8 b1v = *(const s16x8*)(b2p + 131072 + ((size_t)l0 << 3));   // n += 32
            f32x4 cfr = MFMA16(a0f, b0, zero);
            cfr = MFMA16(a1f, b1v, cfr);
#pragma unroll
            for (int r = 0; r < 4; ++r)
                sm.ctile[p][q * 4 + r][wave * 64 + t * 16 + l16] = cfr[r];
        }
        // prefetch next chunk's x before the barrier (in flight during RMW)
        if (lc < 15) {
#pragma unroll
            for (int rr = 0; rr < 4; ++rr)
                xr2[rr] = *(const f32x4*)(xep + (size_t)rr * L_DIM + (lc + 1) * 256);
        }
        asm volatile("s_waitcnt lgkmcnt(0)" ::: "memory");
        __builtin_amdgcn_s_barrier();

        // cooperative RMW: wave owns rows srow..srow+3, 1 KB contiguous each.
        // Next iter's ctile writes go to buffer p^1; writes to p recur only
        // after the NEXT barrier -> single barrier per chunk is race-free.
#pragma unroll
        for (int rr = 0; rr < 4; ++rr) {
            f32x4 cc = *(const f32x4*)&sm.ctile[p][srow + rr][lane * 4];
            *(f32x4*)(oep + (size_t)rr * L_DIM + lc * 256) = xr[rr] + cc;
        }
#pragma unroll
        for (int rr = 0; rr < 4; ++rr) xr[rr] = xr2[rr];
    }
}

// ---------------------------------------------------------------------------
extern "C" void kernel_launch(void* const* d_in, const int* in_sizes, int n_in,
                              void* d_out, int out_size, void* d_ws, size_t ws_size,
                              hipStream_t stream) {
    const float* x = (const float*)d_in[0];
    float* out = (float*)d_out;

    // workspace: 3 pre-swizzled basis arrays, 64*4096 bf16 each (512 KiB each)
    ushort* b1h = (ushort*)d_ws;
    ushort* b1l = b1h + (size_t)N_BASIS * L_DIM;
    ushort* b2h = b1l + (size_t)N_BASIS * L_DIM;

    // ws is re-poisoned before every launch -> rebuild basis every call
    afd_basis_kernel<<<(N_BASIS * L_DIM) / 256, 256, 0, stream>>>(b1h, b1l, b2h);
    afd_main_kernel<<<BC / 16, 256, 0, stream>>>(x, out, b1h, b1l, b2h);
}